// Round 1
// baseline (201927.441 us; speedup 1.0000x reference)
//
#include <hip/hip_runtime.h>
#include <cstddef>

// Problem constants (fixed by reference)
#define BB  32
#define TT  2048
#define DIM 512
#define HH  1024

__device__ __forceinline__ float sigmoidf_(float x) {
    // __expf(+-inf) saturates correctly -> sigmoid limits are exact
    return 1.f / (1.f + __expf(-x));
}
__device__ __forceinline__ float tanhf_(float x) {
    float c = fminf(fmaxf(x, -15.f), 15.f);   // avoid inf/inf
    float e = __expf(2.f * c);
    return (e - 1.f) / (e + 1.f);
}

// ---------------- setup kernels ----------------

// zero h buffers + barrier, transpose x0 -> xT[d][b]
__global__ void k_init(const float* __restrict__ x0, float* __restrict__ xT,
                       float* __restrict__ ha, float* __restrict__ hb,
                       unsigned* __restrict__ bar) {
    int i = blockIdx.x * blockDim.x + threadIdx.x;
    if (i < DIM * BB) { int d = i >> 5, b = i & 31; xT[d * BB + b] = x0[b * DIM + d]; }
    if (i < HH * BB) { ha[i] = 0.f; hb[i] = 0.f; }
    if (i < 64) bar[i] = 0u;
}

// Wc[i][d] = sum_k W_ih[i][k] * W_enc[k][d]   (i<3072, d<512, k<1024)
__global__ void k_wc(const float* __restrict__ Wih, const float* __restrict__ Wenc,
                     float* __restrict__ Wc) {
    int db = blockIdx.x & 7, ib = blockIdx.x >> 3;
    int d = db * 64 + (threadIdx.x & 63);
    int i = ib * 4 + (threadIdx.x >> 6);
    const float4* wi4 = (const float4*)(Wih + (size_t)i * HH);
    float acc = 0.f;
    for (int k4 = 0; k4 < HH / 4; ++k4) {
        float4 w = wi4[k4];
        int k = k4 * 4;
        acc += w.x * Wenc[(size_t)(k + 0) * DIM + d];
        acc += w.y * Wenc[(size_t)(k + 1) * DIM + d];
        acc += w.z * Wenc[(size_t)(k + 2) * DIM + d];
        acc += w.w * Wenc[(size_t)(k + 3) * DIM + d];
    }
    Wc[(size_t)i * DIM + d] = acc;
}

// bc[i] = sum_k W_ih[i][k] * b_enc[k] + b_gru[i]
__global__ void k_bc(const float* __restrict__ Wih, const float* __restrict__ benc,
                     const float* __restrict__ bgru, float* __restrict__ bc) {
    int i = blockIdx.x;
    float s = 0.f;
    for (int k = threadIdx.x; k < HH; k += 256) s += Wih[(size_t)i * HH + k] * benc[k];
    __shared__ float red[256];
    red[threadIdx.x] = s; __syncthreads();
    for (int off = 128; off > 0; off >>= 1) {
        if (threadIdx.x < off) red[threadIdx.x] += red[threadIdx.x + off];
        __syncthreads();
    }
    if (threadIdx.x == 0) bc[i] = red[0] + bgru[i];
}

// ---------------- persistent recurrent kernel ----------------

// device-scope sense-reversing grid barrier; bar[0]=count, bar[32]=epoch-release
__device__ __forceinline__ void gbar(unsigned* bar, unsigned* epoch, int nblk) {
    __syncthreads();
    if (threadIdx.x == 0) {
        __threadfence();
        unsigned e = ++(*epoch);
        unsigned old = __hip_atomic_fetch_add(&bar[0], 1u, __ATOMIC_ACQ_REL,
                                              __HIP_MEMORY_SCOPE_AGENT);
        if (old == (unsigned)(nblk - 1)) {
            __hip_atomic_store(&bar[0], 0u, __ATOMIC_RELAXED, __HIP_MEMORY_SCOPE_AGENT);
            __hip_atomic_store(&bar[32], e, __ATOMIC_RELEASE, __HIP_MEMORY_SCOPE_AGENT);
        } else {
            while (__hip_atomic_load(&bar[32], __ATOMIC_ACQUIRE,
                                     __HIP_MEMORY_SCOPE_AGENT) < e) {
                __builtin_amdgcn_s_sleep(2);
            }
        }
        __threadfence();
    }
    __syncthreads();
}

__global__ void __launch_bounds__(256) k_gru(
    const float* __restrict__ Wc, const float* __restrict__ bc,
    const float* __restrict__ Whh, const float* __restrict__ Wdec,
    const float* __restrict__ bn, const float* __restrict__ bdec,
    const float* __restrict__ eps, float* __restrict__ xT,
    float* __restrict__ ha, float* __restrict__ hb,
    float* __restrict__ out, unsigned* __restrict__ bar)
{
    const int tid = threadIdx.x;
    const int b = tid & 31;
    const int q = tid >> 5;          // 0..7
    const int nblk = gridDim.x;
    unsigned epoch = 0;

    __shared__ float exA[4][BB][6];
    __shared__ float exB[2][BB][2][2];

    // ---- phase A mapping: 4 j per block, 2-way K-split (v) ----
    const int jj = q & 3, v = q >> 2;                 // v uniform per wave
    const int j = (blockIdx.x << 2) + jj;             // j in [0,1024)
    const float4* wr4 = (const float4*)(Wc + (size_t)j * DIM);
    const float4* wz4 = (const float4*)(Wc + (size_t)(j + HH) * DIM);
    const float4* wn4 = (const float4*)(Wc + (size_t)(j + 2 * HH) * DIM);
    const float4* ur4 = (const float4*)(Whh + (size_t)j * HH);
    const float4* uz4 = (const float4*)(Whh + (size_t)(j + HH) * HH);
    const float4* un4 = (const float4*)(Whh + (size_t)(j + 2 * HH) * HH);
    const float bcr = bc[j], bcz = bc[j + HH], bcn = bc[j + 2 * HH];
    const float bnj = bn[j];

    // ---- phase B mapping: 2 d per block, mu/log_std (which), 2-way K-split (kv) ----
    const int dd = q >> 2, which = q & 1, kv = (q >> 1) & 1;
    const int dcol = (blockIdx.x << 1) + dd;          // d in [0,512)
    const float4* wd4 = (const float4*)(Wdec + (size_t)(dcol + which * DIM) * HH);

    const size_t TBD = (size_t)TT * BB * DIM;

    for (int t = 0; t < TT; ++t) {
        const float* __restrict__ hcur = (t & 1) ? hb : ha;
        float* __restrict__ hnew = (t & 1) ? ha : hb;

        // ================= phase A: gates -> h_new =================
        {
            float ar = 0.f, az = 0.f, an = 0.f, pr = 0.f, pz = 0.f, pn = 0.f;
            const int x40 = v * (DIM / 8);
            for (int k4 = x40; k4 < x40 + DIM / 8; ++k4) {
                float4 wr = wr4[k4], wz = wz4[k4], wn = wn4[k4];
                int k = k4 * 4;
                float x0v = xT[(k + 0) * BB + b];
                float x1v = xT[(k + 1) * BB + b];
                float x2v = xT[(k + 2) * BB + b];
                float x3v = xT[(k + 3) * BB + b];
                ar += wr.x * x0v; ar += wr.y * x1v; ar += wr.z * x2v; ar += wr.w * x3v;
                az += wz.x * x0v; az += wz.y * x1v; az += wz.z * x2v; az += wz.w * x3v;
                an += wn.x * x0v; an += wn.y * x1v; an += wn.z * x2v; an += wn.w * x3v;
            }
            const int h40 = v * (HH / 8);
            for (int k4 = h40; k4 < h40 + HH / 8; ++k4) {
                float4 ur = ur4[k4], uz = uz4[k4], un = un4[k4];
                int k = k4 * 4;
                float h0v = hcur[(k + 0) * BB + b];
                float h1v = hcur[(k + 1) * BB + b];
                float h2v = hcur[(k + 2) * BB + b];
                float h3v = hcur[(k + 3) * BB + b];
                pr += ur.x * h0v; pr += ur.y * h1v; pr += ur.z * h2v; pr += ur.w * h3v;
                pz += uz.x * h0v; pz += uz.y * h1v; pz += uz.z * h2v; pz += uz.w * h3v;
                pn += un.x * h0v; pn += un.y * h1v; pn += un.z * h2v; pn += un.w * h3v;
            }
            if (v == 0) {
                exA[jj][b][0] = ar; exA[jj][b][1] = az; exA[jj][b][2] = an;
                exA[jj][b][3] = pr; exA[jj][b][4] = pz; exA[jj][b][5] = pn;
            }
            __syncthreads();
            if (v == 1) {
                ar += exA[jj][b][0]; az += exA[jj][b][1]; an += exA[jj][b][2];
                pr += exA[jj][b][3]; pz += exA[jj][b][4]; pn += exA[jj][b][5];
                float r = sigmoidf_(ar + bcr + pr);
                float z = sigmoidf_(az + bcz + pz);
                float n = tanhf_(an + bcn + r * (pn + bnj));
                float hold = hcur[(size_t)j * BB + b];
                hnew[(size_t)j * BB + b] = n + z * (hold - n);
            }
        }
        gbar(bar, &epoch, nblk);

        // ================= phase B: decoder -> outputs + x_next =================
        {
            float acc = 0.f;
            const int k40 = kv * (HH / 8);
            for (int k4 = k40; k4 < k40 + HH / 8; ++k4) {
                float4 w = wd4[k4];
                int k = k4 * 4;
                acc += w.x * hnew[(k + 0) * BB + b];
                acc += w.y * hnew[(k + 1) * BB + b];
                acc += w.z * hnew[(k + 2) * BB + b];
                acc += w.w * hnew[(k + 3) * BB + b];
            }
            exB[dd][b][which][kv] = acc;
            __syncthreads();
            if (which == 0 && kv == 0) {
                float mu = exB[dd][b][0][0] + exB[dd][b][0][1] + bdec[dcol];
                float ls = exB[dd][b][1][0] + exB[dd][b][1][1] + bdec[dcol + DIM];
                float sg = __expf(ls);
                size_t o = ((size_t)t * BB + b) * DIM + dcol;
                float ev = eps[o];
                float xn = mu + sg * ev;
                out[o] = xn;
                out[TBD + o] = mu;
                out[2 * TBD + o] = sg;
                xT[(size_t)dcol * BB + b] = xn;
            }
        }
        gbar(bar, &epoch, nblk);
    }
}

// ---------------- launch ----------------

extern "C" void kernel_launch(void* const* d_in, const int* in_sizes, int n_in,
                              void* d_out, int out_size, void* d_ws, size_t ws_size,
                              hipStream_t stream) {
    const float* x0   = (const float*)d_in[0];
    const float* eps  = (const float*)d_in[1];
    const float* Wenc = (const float*)d_in[2];
    const float* benc = (const float*)d_in[3];
    const float* Wih  = (const float*)d_in[4];
    const float* Whh  = (const float*)d_in[5];
    const float* bgru = (const float*)d_in[6];
    const float* bn   = (const float*)d_in[7];
    const float* Wdec = (const float*)d_in[8];
    const float* bdec = (const float*)d_in[9];
    float* out = (float*)d_out;

    // workspace layout (floats): Wc | bc | xT | ha | hb | bar  (~6.3 MB)
    float* ws = (float*)d_ws;
    float* Wc = ws;
    float* bc = Wc + (size_t)3 * HH * DIM;   // 1,572,864
    float* xT = bc + 3 * HH;                 // + 3072
    float* ha = xT + DIM * BB;               // + 16384
    float* hb = ha + HH * BB;                // + 32768
    unsigned* bar = (unsigned*)(hb + HH * BB);

    hipLaunchKernelGGL(k_init, dim3(128), dim3(256), 0, stream, x0, xT, ha, hb, bar);
    hipLaunchKernelGGL(k_wc, dim3(6144), dim3(256), 0, stream, Wih, Wenc, Wc);
    hipLaunchKernelGGL(k_bc, dim3(3072), dim3(256), 0, stream, Wih, benc, bgru, bc);

    void* args[] = { &Wc, &bc, (void*)&Whh, (void*)&Wdec, (void*)&bn, (void*)&bdec,
                     (void*)&eps, &xT, &ha, &hb, &out, &bar };
    hipLaunchCooperativeKernel((void*)k_gru, dim3(256), dim3(256), args, 0, stream);
}